// Round 17
// baseline (57.167 us; speedup 1.0000x reference)
//
#include <hip/hip_runtime.h>
#include <hip/hip_bf16.h>

typedef __attribute__((ext_vector_type(8))) short bf16x8;
typedef __attribute__((ext_vector_type(4))) float f32x4;

#define NB   4
#define NN   2048
#define FIN  256
#define FOUT 128
#define SPLIT 8
#define JCH  (NN / SPLIT)      // 256 j per block
#define NSTEP (JCH / 64)       // 4 steps of 64 j

__device__ __forceinline__ unsigned short f2bf(float f) {
    unsigned int u = __builtin_bit_cast(unsigned int, f);
    u += 0x7fffu + ((u >> 16) & 1u);
    return (unsigned short)(u >> 16);
}

// ---------------- Kernel 0: WT[o][k] bf16 from W[k][o] f32 ----------------
__global__ __launch_bounds__(256) void k_wt(const float* __restrict__ W,
                                            unsigned short* __restrict__ WT) {
    int idx = blockIdx.x * 256 + threadIdx.x;
    int k = idx & 255, o = idx >> 8;
    WT[idx] = f2bf(W[k * FOUT + o]);
}

// ---------------- Kernel 1: Wh = h@W; writes B-FRAGMENT-ORDER WhB + s1,s2 -
__global__ __launch_bounds__(256) void k_wh(const float* __restrict__ h,
                                            const float* __restrict__ a,
                                            const unsigned short* __restrict__ WT,
                                            unsigned short* __restrict__ WhB,
                                            float* __restrict__ s1,
                                            float* __restrict__ s2) {
    __shared__ unsigned short hs[16][264];
    __shared__ float s1w[4][16], s2w[4][16];
    int t = threadIdx.x, blk = blockIdx.x;
    int nglob0 = blk * 16;
    int b = nglob0 >> 11;

    const float4* h4 = (const float4*)h + (size_t)blk * 1024;
    #pragma unroll
    for (int i = 0; i < 4; ++i) {
        int idx = i * 256 + t;
        float4 v = h4[idx];
        int row = idx >> 6, c4 = (idx & 63) * 4;
        unsigned int lo = (unsigned int)f2bf(v.x) | ((unsigned int)f2bf(v.y) << 16);
        unsigned int hi = (unsigned int)f2bf(v.z) | ((unsigned int)f2bf(v.w) << 16);
        *(uint2*)&hs[row][c4] = make_uint2(lo, hi);
    }
    __syncthreads();

    int w = t >> 6, l = t & 63, lr = l & 15, lk = l >> 4;
    float a1v[2], a2v[2];
    #pragma unroll
    for (int j = 0; j < 2; ++j) {
        a1v[j] = a[(w * 2 + j) * 16 + lr];
        a2v[j] = a[FOUT + (w * 2 + j) * 16 + lr];
    }
    f32x4 acc[2] = {{0.f,0.f,0.f,0.f},{0.f,0.f,0.f,0.f}};

    #pragma unroll
    for (int kk = 0; kk < 8; ++kk) {
        int k0 = kk * 32;
        bf16x8 af = *(const bf16x8*)&hs[lr][k0 + lk * 8];
        #pragma unroll
        for (int j = 0; j < 2; ++j) {
            bf16x8 bfr = *(const bf16x8*)(WT + ((w * 2 + j) * 16 + lr) * 256 + k0 + lk * 8);
            acc[j] = __builtin_amdgcn_mfma_f32_16x16x32_bf16(af, bfr, acc[j], 0, 0, 0);
        }
    }

    int n0 = nglob0 & 2047;
    int sIdx = n0 >> 6;
    int hh   = (n0 >> 5) & 1;
    int bklo = (n0 & 31) >> 3;
    float v1[4] = {0.f,0.f,0.f,0.f}, v2[4] = {0.f,0.f,0.f,0.f};
    #pragma unroll
    for (int j = 0; j < 2; ++j) {
        int ot = w * 2 + j;
        float x0 = acc[j][0], x1 = acc[j][1], x2 = acc[j][2], x3 = acc[j][3];
        ushort4 pk;
        pk.x = f2bf(x0); pk.y = f2bf(x1); pk.z = f2bf(x2); pk.w = f2bf(x3);
        size_t fragBase = (((size_t)(b * 8 + ot) * 32 + sIdx) * 2 + hh) * 64;
        size_t lane = fragBase + lr + 16 * (bklo + (lk >> 1));
        *(ushort4*)(WhB + lane * 8 + (lk & 1) * 4) = pk;
        v1[0] += x0 * a1v[j]; v1[1] += x1 * a1v[j]; v1[2] += x2 * a1v[j]; v1[3] += x3 * a1v[j];
        v2[0] += x0 * a2v[j]; v2[1] += x1 * a2v[j]; v2[2] += x2 * a2v[j]; v2[3] += x3 * a2v[j];
    }
    #pragma unroll
    for (int m = 1; m < 16; m <<= 1)
        #pragma unroll
        for (int r = 0; r < 4; ++r) {
            v1[r] += __shfl_xor(v1[r], m);
            v2[r] += __shfl_xor(v2[r], m);
        }
    if (lr == 0)
        #pragma unroll
        for (int r = 0; r < 4; ++r) {
            s1w[w][lk * 4 + r] = v1[r];
            s2w[w][lk * 4 + r] = v2[r];
        }
    __syncthreads();
    if (t < 16) {
        s1[nglob0 + t] = s1w[0][t] + s1w[1][t] + s1w[2][t] + s1w[3][t];
        s2[nglob0 + t] = s2w[0][t] + s2w[1][t] + s2w[2][t] + s2w[3][t];
    }
}

// ---------------- Kernel 2: attention — SPLIT=8, 16 waves/CU --------------
// 1024 blocks x 256 thr. Block: 64 i x 256 j-chunk x ALL 128 o.
// 2x occupancy vs R16 (the 80%-stall residual). LDS cut: no hS transpose
// (direct acc stores); Ps pad 76 (fixes 4-way MFMA-read conflict).
__global__ __launch_bounds__(256) void k_attn(const int* __restrict__ adj,
                                              const unsigned short* __restrict__ WhB,
                                              const float* __restrict__ s1,
                                              const float* __restrict__ s2,
                                              float* __restrict__ num,
                                              float* __restrict__ Zp) {
    __shared__ union {
        unsigned short Ps[2][64][76];              // P tile bf16, dbuf (19.5 KB)
        unsigned char sc[4][1024];                 // prologue pack scratch (4 KB)
    } S;
    __shared__ unsigned int nibS[64][17];          // 64 rows x 8 dwords, pad 17
    __shared__ float s2S[JCH];                     // 1 KB

    int t = threadIdx.x, w = t >> 6, l = t & 63, lr = l & 15, lk = l >> 4;
    int bi = blockIdx.x;
    int part = bi >> 7, rem = bi & 127;            // part 0..7
    int b = rem >> 5, i0 = (rem & 31) * 64, j0 = part * JCH;

    // ---- prologue: wave w packs adj rows [i0+w*16,+16) x [j0, j0+256) ----
    {
        unsigned char* sh = S.sc[w];               // 16 rows x 64 B
        const int* aBase = adj + ((size_t)(b * NN) + i0 + w * 16) * NN + j0;
        #pragma unroll
        for (int batch = 0; batch < 4; ++batch) {
            int4 v[4];
            #pragma unroll
            for (int r = 0; r < 4; ++r)
                v[r] = *(const int4*)(aBase + (size_t)(batch * 4 + r) * NN + l * 4);
            #pragma unroll
            for (int r = 0; r < 4; ++r) {
                unsigned char nb = (unsigned char)((v[r].x > 0) | ((v[r].y > 0) << 1) |
                                                   ((v[r].z > 0) << 2) | ((v[r].w > 0) << 3));
                sh[(batch * 4 + r) * 64 + l] = nb;
            }
        }
        asm volatile("s_waitcnt lgkmcnt(0)" ::: "memory");   // wave-local bytes
        // read back: 16 rows x 8 dwords = 128 per wave; lane handles 2
        #pragma unroll
        for (int q = 0; q < 2; ++q) {
            int d = q * 64 + l;                    // 0..127
            int row = d >> 3, c = d & 7;
            uint2 u = *(const uint2*)&sh[row * 64 + c * 8];
            unsigned int lo = (u.x & 0xFu) | ((u.x >> 4) & 0xF0u) |
                              ((u.x >> 8) & 0xF00u) | ((u.x >> 12) & 0xF000u);
            unsigned int hi = (u.y & 0xFu) | ((u.y >> 4) & 0xF0u) |
                              ((u.y >> 8) & 0xF00u) | ((u.y >> 12) & 0xF000u);
            nibS[w * 16 + row][c] = lo | (hi << 16);
        }
        if (t < 64) ((float4*)s2S)[t] = ((const float4*)(s2 + b * NN + j0))[t];
    }
    float s1r = s1[b * NN + i0 + w * 16 + lr];

    // ---- B prefetch: wave w covers ot = 2w, 2w+1; 2-deep ring in regs ----
    const unsigned short* B0 = WhB + (((size_t)(b * 8 + w * 2) * 32 + part * NSTEP) * 2) * 512 + (size_t)l * 8;
    const unsigned short* B1 = B0 + (size_t)32 * 2 * 512;   // next ot
    bf16x8 bB[2][2][2];                            // [buf][ot2][hh]
    #pragma unroll
    for (int s = 0; s < 2; ++s) {
        bB[s][0][0] = *(const bf16x8*)(B0 + s * 1024);
        bB[s][0][1] = *(const bf16x8*)(B0 + s * 1024 + 512);
        bB[s][1][0] = *(const bf16x8*)(B1 + s * 1024);
        bB[s][1][1] = *(const bf16x8*)(B1 + s * 1024 + 512);
    }

    f32x4 acc[4][2];
    #pragma unroll
    for (int rg = 0; rg < 4; ++rg) {
        acc[rg][0] = (f32x4){0.f,0.f,0.f,0.f};
        acc[rg][1] = (f32x4){0.f,0.f,0.f,0.f};
    }
    float zacc = 0.f;

    __syncthreads();                               // pack + staging visible; scratch dead

    #pragma unroll
    for (int s = 0; s < NSTEP; ++s) {
        const int slot = s & 1;
        // ---- P-phase: wave's 16 rows; lane = (row lr, j lk*16..+15) ----
        {
            unsigned int word = nibS[w * 16 + lr][s * 2 + (lk >> 1)] >> ((lk & 1) * 16);
            const float* sp = &s2S[s * 64 + lk * 16];
            float4 f0 = *(const float4*)sp,       f1 = *(const float4*)(sp + 4);
            float4 f2 = *(const float4*)(sp + 8), f3 = *(const float4*)(sp + 12);
            float sv[16] = {f0.x,f0.y,f0.z,f0.w, f1.x,f1.y,f1.z,f1.w,
                            f2.x,f2.y,f2.z,f2.w, f3.x,f3.y,f3.z,f3.w};
            unsigned int pw[8];
            #pragma unroll
            for (int q = 0; q < 8; ++q) {
                float e0 = s1r + sv[2 * q];
                float e1 = s1r + sv[2 * q + 1];
                e0 = fmaxf(e0, 0.2f * e0);
                e1 = fmaxf(e1, 0.2f * e1);
                float p0 = ((word >> (2 * q))     & 1u) ? __expf(e0) : 0.f;
                float p1 = ((word >> (2 * q + 1)) & 1u) ? __expf(e1) : 0.f;
                zacc += p0 + p1;
                pw[q] = (unsigned int)f2bf(p0) | ((unsigned int)f2bf(p1) << 16);
            }
            *(uint4*)&S.Ps[slot][w * 16 + lr][lk * 16]     = (uint4){pw[0], pw[1], pw[2], pw[3]};
            *(uint4*)&S.Ps[slot][w * 16 + lr][lk * 16 + 8] = (uint4){pw[4], pw[5], pw[6], pw[7]};
        }
        asm volatile("s_waitcnt lgkmcnt(0)" ::: "memory");
        __builtin_amdgcn_s_barrier();
        __builtin_amdgcn_sched_barrier(0);

        // ---- copy B to locals, refill ring slot (independent, no drain) ----
        bf16x8 c00 = bB[slot][0][0], c01 = bB[slot][0][1];
        bf16x8 c10 = bB[slot][1][0], c11 = bB[slot][1][1];
        if (s < NSTEP - 2) {
            bB[slot][0][0] = *(const bf16x8*)(B0 + (s + 2) * 1024);
            bB[slot][0][1] = *(const bf16x8*)(B0 + (s + 2) * 1024 + 512);
            bB[slot][1][0] = *(const bf16x8*)(B1 + (s + 2) * 1024);
            bB[slot][1][1] = *(const bf16x8*)(B1 + (s + 2) * 1024 + 512);
        }

        // ---- MFMA: 4 row-groups x 2 ot x 2 hh = 16 MFMAs ----
        #pragma unroll
        for (int rg = 0; rg < 4; ++rg) {
            bf16x8 a0 = *(const bf16x8*)&S.Ps[slot][rg * 16 + lr][lk * 8];
            bf16x8 a1 = *(const bf16x8*)&S.Ps[slot][rg * 16 + lr][32 + lk * 8];
            acc[rg][0] = __builtin_amdgcn_mfma_f32_16x16x32_bf16(a0, c00, acc[rg][0], 0, 0, 0);
            acc[rg][0] = __builtin_amdgcn_mfma_f32_16x16x32_bf16(a1, c01, acc[rg][0], 0, 0, 0);
            acc[rg][1] = __builtin_amdgcn_mfma_f32_16x16x32_bf16(a0, c10, acc[rg][1], 0, 0, 0);
            acc[rg][1] = __builtin_amdgcn_mfma_f32_16x16x32_bf16(a1, c11, acc[rg][1], 0, 0, 0);
        }
    }

    // ---- Z partial for wave's rows (sum over lk) ----
    zacc += __shfl_xor(zacc, 16);
    zacc += __shfl_xor(zacc, 32);
    if (l < 16) Zp[(size_t)(part * NB + b) * NN + i0 + w * 16 + l] = zacc;

    // ---- epilogue: direct acc stores (64 B segments per 16 lanes) ----
    float* npb = num + ((size_t)(part * NB + b) * NN + i0) * FOUT;
    #pragma unroll
    for (int rg = 0; rg < 4; ++rg)
        #pragma unroll
        for (int ot2 = 0; ot2 < 2; ++ot2)
            #pragma unroll
            for (int r = 0; r < 4; ++r)
                npb[(size_t)(rg * 16 + lk * 4 + r) * FOUT + (w * 2 + ot2) * 16 + lr]
                    = acc[rg][ot2][r];
}

// ---------------- Kernel 3: reduce splits + LayerNorm + GELU --------------
__global__ __launch_bounds__(256) void k_final(const float* __restrict__ num,
                                               const float* __restrict__ Zp,
                                               const float* __restrict__ gamma,
                                               const float* __restrict__ beta,
                                               float* __restrict__ out) {
    int t = threadIdx.x, bi = blockIdx.x;
    int rowA = t >> 5;
    int c0 = (t & 31) * 4;
    size_t gn = (size_t)bi * 8 + rowA;
    int b = (int)(gn >> 11), n = (int)(gn & 2047);

    float Z = 0.f;
    #pragma unroll
    for (int p = 0; p < SPLIT; ++p) Z += Zp[(size_t)(p * NB + b) * NN + n];

    float x[4] = {0.f, 0.f, 0.f, 0.f};
    #pragma unroll
    for (int p = 0; p < SPLIT; ++p) {
        const float* np = num + ((size_t)(p * NB + b) * NN + n) * FOUT + c0;
        float4 v0 = *(const float4*)np;
        x[0] += v0.x; x[1] += v0.y; x[2] += v0.z; x[3] += v0.w;
    }
    float rz = 1.f / Z;
    #pragma unroll
    for (int i = 0; i < 4; ++i) x[i] *= rz;

    float sm = 0.f, sq = 0.f;
    #pragma unroll
    for (int i = 0; i < 4; ++i) { sm += x[i]; sq += x[i] * x[i]; }
    #pragma unroll
    for (int m = 1; m < 32; m <<= 1) {
        sm += __shfl_xor(sm, m);
        sq += __shfl_xor(sq, m);
    }
    float mu  = sm * (1.f / 128.f);
    float var = sq * (1.f / 128.f) - mu * mu;
    float rs  = rsqrtf(var + 1e-5f);
    float4 g0 = *(const float4*)(gamma + c0);
    float4 e0 = *(const float4*)(beta + c0);
    float gg[4] = {g0.x, g0.y, g0.z, g0.w};
    float bb[4] = {e0.x, e0.y, e0.z, e0.w};
    float y[4];
    #pragma unroll
    for (int i = 0; i < 4; ++i) {
        float v = (x[i] - mu) * rs * gg[i] + bb[i];
        y[i] = 0.5f * v * (1.f + erff(v * 0.70710678118f));
    }
    float* op = out + gn * FOUT + c0;
    *(float4*)op = make_float4(y[0], y[1], y[2], y[3]);
}

// ---------------- launcher ----------------
extern "C" void kernel_launch(void* const* d_in, const int* in_sizes, int n_in,
                              void* d_out, int out_size, void* d_ws, size_t ws_size,
                              hipStream_t stream) {
    const float* h     = (const float*)d_in[0];
    const int*   adj   = (const int*)d_in[1];
    const float* W     = (const float*)d_in[2];
    const float* a     = (const float*)d_in[3];
    const float* gamma = (const float*)d_in[4];
    const float* beta  = (const float*)d_in[5];
    float* out = (float*)d_out;

    char* ws = (char*)d_ws;
    unsigned short* WT  = (unsigned short*)ws;                       // 64 KiB
    unsigned short* WhB = (unsigned short*)(ws + (1u << 16));        // 2 MiB
    float* s1 = (float*)(ws + 2162688);                              // 32 KiB
    float* s2 = (float*)(ws + 2195456);                              // 32 KiB
    float* Zp = (float*)(ws + 2228224);                              // 256 KiB
    float* num = (float*)(ws + 2490368);                             // 32 MiB

    hipLaunchKernelGGL(k_wt,    dim3(128),  dim3(256), 0, stream, W, WT);
    hipLaunchKernelGGL(k_wh,    dim3(512),  dim3(256), 0, stream, h, a, WT, WhB, s1, s2);
    hipLaunchKernelGGL(k_attn,  dim3(1024), dim3(256), 0, stream, adj, WhB, s1, s2, num, Zp);
    hipLaunchKernelGGL(k_final, dim3(1024), dim3(256), 0, stream, num, Zp, gamma, beta, out);
}

// Round 18
// 46.697 us; speedup vs baseline: 1.2242x; 1.2242x over previous
//
#include <hip/hip_runtime.h>
#include <hip/hip_bf16.h>

typedef __attribute__((ext_vector_type(8))) short bf16x8;
typedef __attribute__((ext_vector_type(4))) float f32x4;

#define NB   4
#define NN   2048
#define FIN  256
#define FOUT 128
#define SPLIT 4
#define JCH  (NN / SPLIT)      // 512 j per block
#define NSTEP (JCH / 64)       // 8 steps of 64 j

__device__ __forceinline__ unsigned short f2bf(float f) {
    unsigned int u = __builtin_bit_cast(unsigned int, f);
    u += 0x7fffu + ((u >> 16) & 1u);
    return (unsigned short)(u >> 16);
}
__device__ __forceinline__ float bf2f(unsigned short s) {
    return __builtin_bit_cast(float, (unsigned int)s << 16);
}

// ---------------- Kernel 0: WT[o][k] bf16 from W[k][o] f32 ----------------
__global__ __launch_bounds__(256) void k_wt(const float* __restrict__ W,
                                            unsigned short* __restrict__ WT) {
    int idx = blockIdx.x * 256 + threadIdx.x;
    int k = idx & 255, o = idx >> 8;
    WT[idx] = f2bf(W[k * FOUT + o]);
}

// ---------------- Kernel 1: Wh = h@W; writes B-FRAGMENT-ORDER WhB + s1,s2 -
__global__ __launch_bounds__(256) void k_wh(const float* __restrict__ h,
                                            const float* __restrict__ a,
                                            const unsigned short* __restrict__ WT,
                                            unsigned short* __restrict__ WhB,
                                            float* __restrict__ s1,
                                            float* __restrict__ s2) {
    __shared__ unsigned short hs[16][264];
    __shared__ float s1w[4][16], s2w[4][16];
    int t = threadIdx.x, blk = blockIdx.x;
    int nglob0 = blk * 16;
    int b = nglob0 >> 11;

    const float4* h4 = (const float4*)h + (size_t)blk * 1024;
    #pragma unroll
    for (int i = 0; i < 4; ++i) {
        int idx = i * 256 + t;
        float4 v = h4[idx];
        int row = idx >> 6, c4 = (idx & 63) * 4;
        unsigned int lo = (unsigned int)f2bf(v.x) | ((unsigned int)f2bf(v.y) << 16);
        unsigned int hi = (unsigned int)f2bf(v.z) | ((unsigned int)f2bf(v.w) << 16);
        *(uint2*)&hs[row][c4] = make_uint2(lo, hi);
    }
    __syncthreads();

    int w = t >> 6, l = t & 63, lr = l & 15, lk = l >> 4;
    float a1v[2], a2v[2];
    #pragma unroll
    for (int j = 0; j < 2; ++j) {
        a1v[j] = a[(w * 2 + j) * 16 + lr];
        a2v[j] = a[FOUT + (w * 2 + j) * 16 + lr];
    }
    f32x4 acc[2] = {{0.f,0.f,0.f,0.f},{0.f,0.f,0.f,0.f}};

    #pragma unroll
    for (int kk = 0; kk < 8; ++kk) {
        int k0 = kk * 32;
        bf16x8 af = *(const bf16x8*)&hs[lr][k0 + lk * 8];
        #pragma unroll
        for (int j = 0; j < 2; ++j) {
            bf16x8 bfr = *(const bf16x8*)(WT + ((w * 2 + j) * 16 + lr) * 256 + k0 + lk * 8);
            acc[j] = __builtin_amdgcn_mfma_f32_16x16x32_bf16(af, bfr, acc[j], 0, 0, 0);
        }
    }

    int n0 = nglob0 & 2047;
    int sIdx = n0 >> 6;
    int hh   = (n0 >> 5) & 1;
    int bklo = (n0 & 31) >> 3;
    float v1[4] = {0.f,0.f,0.f,0.f}, v2[4] = {0.f,0.f,0.f,0.f};
    #pragma unroll
    for (int j = 0; j < 2; ++j) {
        int ot = w * 2 + j;
        float x0 = acc[j][0], x1 = acc[j][1], x2 = acc[j][2], x3 = acc[j][3];
        ushort4 pk;
        pk.x = f2bf(x0); pk.y = f2bf(x1); pk.z = f2bf(x2); pk.w = f2bf(x3);
        size_t fragBase = (((size_t)(b * 8 + ot) * 32 + sIdx) * 2 + hh) * 64;
        size_t lane = fragBase + lr + 16 * (bklo + (lk >> 1));
        *(ushort4*)(WhB + lane * 8 + (lk & 1) * 4) = pk;
        v1[0] += x0 * a1v[j]; v1[1] += x1 * a1v[j]; v1[2] += x2 * a1v[j]; v1[3] += x3 * a1v[j];
        v2[0] += x0 * a2v[j]; v2[1] += x1 * a2v[j]; v2[2] += x2 * a2v[j]; v2[3] += x3 * a2v[j];
    }
    #pragma unroll
    for (int m = 1; m < 16; m <<= 1)
        #pragma unroll
        for (int r = 0; r < 4; ++r) {
            v1[r] += __shfl_xor(v1[r], m);
            v2[r] += __shfl_xor(v2[r], m);
        }
    if (lr == 0)
        #pragma unroll
        for (int r = 0; r < 4; ++r) {
            s1w[w][lk * 4 + r] = v1[r];
            s2w[w][lk * 4 + r] = v2[r];
        }
    __syncthreads();
    if (t < 16) {
        s1[nglob0 + t] = s1w[0][t] + s1w[1][t] + s1w[2][t] + s1w[3][t];
        s2[nglob0 + t] = s2w[0][t] + s2w[1][t] + s2w[2][t] + s2w[3][t];
    }
}

// ---------------- Kernel 2: attention — XCD-swizzled, bf16 num ------------
// R16 structure (best). NEW: (1) bijective XCD swizzle so the 32 blocks
// sharing each (part,b) 128 KB WhB panel land on ONE XCD -> B-loads L2-hit
// instead of L3 (T1 mechanism); (2) num stored bf16 (halves roundtrip).
__global__ __launch_bounds__(256) void k_attn(const int* __restrict__ adj,
                                              const unsigned short* __restrict__ WhB,
                                              const float* __restrict__ s1,
                                              const float* __restrict__ s2,
                                              unsigned short* __restrict__ num,
                                              float* __restrict__ Zp) {
    __shared__ union {
        unsigned short Ps[2][64][72];              // P tile bf16, dbuf (18.4 KB)
        float hS[64][132];                         // epilogue transpose (33.8 KB)
        unsigned char sc[4][2048];                 // prologue pack scratch (8 KB)
    } S;
    __shared__ unsigned int nibS[64][20];          // 64 rows x 16 dwords (5 KB)
    __shared__ float s2S[JCH];                     // 2 KB

    int t = threadIdx.x, w = t >> 6, l = t & 63, lr = l & 15, lk = l >> 4;
    // XCD-aware bijective swizzle (grid 512 = 8 * 64): hardware bids
    // {x, x+8, x+16, ...} (one XCD) get 64 consecutive logical blocks.
    int bid = blockIdx.x;
    int bi = (bid >> 3) + (bid & 7) * 64;
    int part = bi >> 7, rem = bi & 127;
    int b = rem >> 5, i0 = (rem & 31) * 64, j0 = part * JCH;

    // ---- prologue: wave w packs adj rows [i0+w*16, +16) x [j0, j0+512) ----
    {
        unsigned char* sh = S.sc[w];               // 16 rows x 128 B
        const int* aBase = adj + ((size_t)(b * NN) + i0 + w * 16) * NN + j0;
        #pragma unroll
        for (int batch = 0; batch < 4; ++batch) {
            int4 v[4][2];
            #pragma unroll
            for (int r = 0; r < 4; ++r) {
                const int* rp = aBase + (size_t)(batch * 4 + r) * NN + l * 8;
                v[r][0] = *(const int4*)rp;
                v[r][1] = *(const int4*)(rp + 4);
            }
            #pragma unroll
            for (int r = 0; r < 4; ++r) {
                unsigned char b0 = (unsigned char)((v[r][0].x > 0) | ((v[r][0].y > 0) << 1) |
                                                   ((v[r][0].z > 0) << 2) | ((v[r][0].w > 0) << 3));
                unsigned char b1 = (unsigned char)((v[r][1].x > 0) | ((v[r][1].y > 0) << 1) |
                                                   ((v[r][1].z > 0) << 2) | ((v[r][1].w > 0) << 3));
                sh[(batch * 4 + r) * 128 + l * 2]     = b0;
                sh[(batch * 4 + r) * 128 + l * 2 + 1] = b1;
            }
        }
        asm volatile("s_waitcnt lgkmcnt(0)" ::: "memory");   // wave-local bytes
        #pragma unroll
        for (int q = 0; q < 4; ++q) {
            int d = q * 64 + l;                    // 0..255
            int row = d >> 4, c = d & 15;
            uint2 u = *(const uint2*)&sh[row * 128 + c * 8];
            unsigned int lo = (u.x & 0xFu) | ((u.x >> 4) & 0xF0u) |
                              ((u.x >> 8) & 0xF00u) | ((u.x >> 12) & 0xF000u);
            unsigned int hi = (u.y & 0xFu) | ((u.y >> 4) & 0xF0u) |
                              ((u.y >> 8) & 0xF00u) | ((u.y >> 12) & 0xF000u);
            nibS[w * 16 + row][c] = lo | (hi << 16);
        }
        if (t < 128) ((float4*)s2S)[t] = ((const float4*)(s2 + b * NN + j0))[t];
    }
    float s1r = s1[b * NN + i0 + w * 16 + lr];

    // ---- B prefetch: wave w covers ot = 2w, 2w+1; 2-deep ring in regs ----
    const unsigned short* B0 = WhB + (((size_t)(b * 8 + w * 2) * 32 + part * NSTEP) * 2) * 512 + (size_t)l * 8;
    const unsigned short* B1 = B0 + (size_t)32 * 2 * 512;   // next ot
    bf16x8 bB[2][2][2];                            // [buf][ot2][hh]
    #pragma unroll
    for (int s = 0; s < 2; ++s) {
        bB[s][0][0] = *(const bf16x8*)(B0 + s * 1024);
        bB[s][0][1] = *(const bf16x8*)(B0 + s * 1024 + 512);
        bB[s][1][0] = *(const bf16x8*)(B1 + s * 1024);
        bB[s][1][1] = *(const bf16x8*)(B1 + s * 1024 + 512);
    }

    f32x4 acc[4][2];
    #pragma unroll
    for (int rg = 0; rg < 4; ++rg) {
        acc[rg][0] = (f32x4){0.f,0.f,0.f,0.f};
        acc[rg][1] = (f32x4){0.f,0.f,0.f,0.f};
    }
    float zacc = 0.f;

    __syncthreads();                               // pack + staging visible; scratch dead

    #pragma unroll
    for (int s = 0; s < NSTEP; ++s) {
        const int slot = s & 1;
        // ---- P-phase: wave's 16 rows; lane = (row lr, j lk*16..+15) ----
        {
            unsigned int word = nibS[w * 16 + lr][s * 2 + (lk >> 1)] >> ((lk & 1) * 16);
            const float* sp = &s2S[s * 64 + lk * 16];
            float4 f0 = *(const float4*)sp,       f1 = *(const float4*)(sp + 4);
            float4 f2 = *(const float4*)(sp + 8), f3 = *(const float4*)(sp + 12);
            float sv[16] = {f0.x,f0.y,f0.z,f0.w, f1.x,f1.y,f1.z,f1.w,
                            f2.x,f2.y,f2.z,f2.w, f3.x,f3.y,f3.z,f3.w};
            unsigned int pw[8];
            #pragma unroll
            for (int q = 0; q < 8; ++q) {
                float e0 = s1r + sv[2 * q];
                float e1 = s1r + sv[2 * q + 1];
                e0 = fmaxf(e0, 0.2f * e0);
                e1 = fmaxf(e1, 0.2f * e1);
                float p0 = ((word >> (2 * q))     & 1u) ? __expf(e0) : 0.f;
                float p1 = ((word >> (2 * q + 1)) & 1u) ? __expf(e1) : 0.f;
                zacc += p0 + p1;
                pw[q] = (unsigned int)f2bf(p0) | ((unsigned int)f2bf(p1) << 16);
            }
            *(uint4*)&S.Ps[slot][w * 16 + lr][lk * 16]     = (uint4){pw[0], pw[1], pw[2], pw[3]};
            *(uint4*)&S.Ps[slot][w * 16 + lr][lk * 16 + 8] = (uint4){pw[4], pw[5], pw[6], pw[7]};
        }
        asm volatile("s_waitcnt lgkmcnt(0)" ::: "memory");
        __builtin_amdgcn_s_barrier();
        __builtin_amdgcn_sched_barrier(0);

        // ---- copy B to locals, refill ring slot (independent, no drain) ----
        bf16x8 c00 = bB[slot][0][0], c01 = bB[slot][0][1];
        bf16x8 c10 = bB[slot][1][0], c11 = bB[slot][1][1];
        if (s < NSTEP - 2) {
            bB[slot][0][0] = *(const bf16x8*)(B0 + (s + 2) * 1024);
            bB[slot][0][1] = *(const bf16x8*)(B0 + (s + 2) * 1024 + 512);
            bB[slot][1][0] = *(const bf16x8*)(B1 + (s + 2) * 1024);
            bB[slot][1][1] = *(const bf16x8*)(B1 + (s + 2) * 1024 + 512);
        }

        // ---- MFMA: 4 row-groups x 2 ot x 2 hh = 16 MFMAs ----
        #pragma unroll
        for (int rg = 0; rg < 4; ++rg) {
            bf16x8 a0 = *(const bf16x8*)&S.Ps[slot][rg * 16 + lr][lk * 8];
            bf16x8 a1 = *(const bf16x8*)&S.Ps[slot][rg * 16 + lr][32 + lk * 8];
            acc[rg][0] = __builtin_amdgcn_mfma_f32_16x16x32_bf16(a0, c00, acc[rg][0], 0, 0, 0);
            acc[rg][0] = __builtin_amdgcn_mfma_f32_16x16x32_bf16(a1, c01, acc[rg][0], 0, 0, 0);
            acc[rg][1] = __builtin_amdgcn_mfma_f32_16x16x32_bf16(a0, c10, acc[rg][1], 0, 0, 0);
            acc[rg][1] = __builtin_amdgcn_mfma_f32_16x16x32_bf16(a1, c11, acc[rg][1], 0, 0, 0);
        }
    }

    // ---- Z partial for wave's rows (sum over lk) ----
    zacc += __shfl_xor(zacc, 16);
    zacc += __shfl_xor(zacc, 32);
    if (l < 16) Zp[(size_t)(part * NB + b) * NN + i0 + w * 16 + l] = zacc;

    // ---- epilogue: acc -> LDS (union reuse) -> coalesced bf16 stores ----
    __syncthreads();                               // Ps dead for all waves
    #pragma unroll
    for (int rg = 0; rg < 4; ++rg)
        #pragma unroll
        for (int ot2 = 0; ot2 < 2; ++ot2)
            #pragma unroll
            for (int r = 0; r < 4; ++r)
                S.hS[rg * 16 + lk * 4 + r][(w * 2 + ot2) * 16 + lr] = acc[rg][ot2][r];
    __syncthreads();

    unsigned short* np = num + ((size_t)(part * NB + b) * NN + i0) * FOUT;
    #pragma unroll
    for (int q = 0; q < 4; ++q) {
        int flat = q * 256 + t;                    // 0..1023
        int row = flat >> 4, c8 = (flat & 15) * 8;
        float4 v0 = *(const float4*)&S.hS[row][c8];
        float4 v1 = *(const float4*)&S.hS[row][c8 + 4];
        uint4 pk;
        pk.x = (unsigned int)f2bf(v0.x) | ((unsigned int)f2bf(v0.y) << 16);
        pk.y = (unsigned int)f2bf(v0.z) | ((unsigned int)f2bf(v0.w) << 16);
        pk.z = (unsigned int)f2bf(v1.x) | ((unsigned int)f2bf(v1.y) << 16);
        pk.w = (unsigned int)f2bf(v1.z) | ((unsigned int)f2bf(v1.w) << 16);
        *(uint4*)(np + (size_t)row * FOUT + c8) = pk;
    }
}

// ---------------- Kernel 3: reduce bf16 splits + LayerNorm + GELU ---------
__global__ __launch_bounds__(256) void k_final(const unsigned short* __restrict__ num,
                                               const float* __restrict__ Zp,
                                               const float* __restrict__ gamma,
                                               const float* __restrict__ beta,
                                               float* __restrict__ out) {
    int t = threadIdx.x, bi = blockIdx.x;
    int rowA = t >> 5;
    int c0 = (t & 31) * 4;
    size_t gn = (size_t)bi * 8 + rowA;
    int b = (int)(gn >> 11), n = (int)(gn & 2047);

    float Z = 0.f;
    #pragma unroll
    for (int p = 0; p < SPLIT; ++p) Z += Zp[(size_t)(p * NB + b) * NN + n];

    float x[4] = {0.f, 0.f, 0.f, 0.f};
    #pragma unroll
    for (int p = 0; p < SPLIT; ++p) {
        const unsigned short* np = num + ((size_t)(p * NB + b) * NN + n) * FOUT + c0;
        ushort4 u = *(const ushort4*)np;
        x[0] += bf2f(u.x); x[1] += bf2f(u.y); x[2] += bf2f(u.z); x[3] += bf2f(u.w);
    }
    float rz = 1.f / Z;
    #pragma unroll
    for (int i = 0; i < 4; ++i) x[i] *= rz;

    float sm = 0.f, sq = 0.f;
    #pragma unroll
    for (int i = 0; i < 4; ++i) { sm += x[i]; sq += x[i] * x[i]; }
    #pragma unroll
    for (int m = 1; m < 32; m <<= 1) {
        sm += __shfl_xor(sm, m);
        sq += __shfl_xor(sq, m);
    }
    float mu  = sm * (1.f / 128.f);
    float var = sq * (1.f / 128.f) - mu * mu;
    float rs  = rsqrtf(var + 1e-5f);
    float4 g0 = *(const float4*)(gamma + c0);
    float4 e0 = *(const float4*)(beta + c0);
    float gg[4] = {g0.x, g0.y, g0.z, g0.w};
    float bb[4] = {e0.x, e0.y, e0.z, e0.w};
    float y[4];
    #pragma unroll
    for (int i = 0; i < 4; ++i) {
        float v = (x[i] - mu) * rs * gg[i] + bb[i];
        y[i] = 0.5f * v * (1.f + erff(v * 0.70710678118f));
    }
    float* op = out + gn * FOUT + c0;
    *(float4*)op = make_float4(y[0], y[1], y[2], y[3]);
}

// ---------------- launcher ----------------
extern "C" void kernel_launch(void* const* d_in, const int* in_sizes, int n_in,
                              void* d_out, int out_size, void* d_ws, size_t ws_size,
                              hipStream_t stream) {
    const float* h     = (const float*)d_in[0];
    const int*   adj   = (const int*)d_in[1];
    const float* W     = (const float*)d_in[2];
    const float* a     = (const float*)d_in[3];
    const float* gamma = (const float*)d_in[4];
    const float* beta  = (const float*)d_in[5];
    float* out = (float*)d_out;

    char* ws = (char*)d_ws;
    unsigned short* WT  = (unsigned short*)ws;                       // 64 KiB
    unsigned short* WhB = (unsigned short*)(ws + (1u << 16));        // 2 MiB
    float* s1 = (float*)(ws + 2162688);                              // 32 KiB
    float* s2 = (float*)(ws + 2195456);                              // 32 KiB
    float* Zp = (float*)(ws + 2228224);                              // 128 KiB
    unsigned short* num = (unsigned short*)(ws + 2359296);           // 8 MiB

    hipLaunchKernelGGL(k_wt,    dim3(128),  dim3(256), 0, stream, W, WT);
    hipLaunchKernelGGL(k_wh,    dim3(512),  dim3(256), 0, stream, h, a, WT, WhB, s1, s2);
    hipLaunchKernelGGL(k_attn,  dim3(512),  dim3(256), 0, stream, adj, WhB, s1, s2, num, Zp);
    hipLaunchKernelGGL(k_final, dim3(1024), dim3(256), 0, stream, num, Zp, gamma, beta, out);
}

// Round 19
// 39.493 us; speedup vs baseline: 1.4475x; 1.1824x over previous
//
#include <hip/hip_runtime.h>
#include <hip/hip_bf16.h>

typedef __attribute__((ext_vector_type(8))) short bf16x8;
typedef __attribute__((ext_vector_type(4))) float f32x4;

#define NB   4
#define NN   2048
#define FIN  256
#define FOUT 128
#define SPLIT 4
#define JCH  (NN / SPLIT)      // 512 j per block
#define NSTEP (JCH / 64)       // 8 steps of 64 j

__device__ __forceinline__ unsigned short f2bf(float f) {
    unsigned int u = __builtin_bit_cast(unsigned int, f);
    u += 0x7fffu + ((u >> 16) & 1u);
    return (unsigned short)(u >> 16);
}
__device__ __forceinline__ float bf2f(unsigned short s) {
    return __builtin_bit_cast(float, (unsigned int)s << 16);
}

// ---------------- Kernel 0: WT[o][k] bf16 from W[k][o] f32 ----------------
__global__ __launch_bounds__(256) void k_wt(const float* __restrict__ W,
                                            unsigned short* __restrict__ WT) {
    int idx = blockIdx.x * 256 + threadIdx.x;
    int k = idx & 255, o = idx >> 8;
    WT[idx] = f2bf(W[k * FOUT + o]);
}

// ---------------- Kernel 1: Wh = h@W; writes B-FRAGMENT-ORDER WhB + s1,s2 -
__global__ __launch_bounds__(256) void k_wh(const float* __restrict__ h,
                                            const float* __restrict__ a,
                                            const unsigned short* __restrict__ WT,
                                            unsigned short* __restrict__ WhB,
                                            float* __restrict__ s1,
                                            float* __restrict__ s2) {
    __shared__ unsigned short hs[16][264];
    __shared__ float s1w[4][16], s2w[4][16];
    int t = threadIdx.x, blk = blockIdx.x;
    int nglob0 = blk * 16;
    int b = nglob0 >> 11;

    const float4* h4 = (const float4*)h + (size_t)blk * 1024;
    #pragma unroll
    for (int i = 0; i < 4; ++i) {
        int idx = i * 256 + t;
        float4 v = h4[idx];
        int row = idx >> 6, c4 = (idx & 63) * 4;
        unsigned int lo = (unsigned int)f2bf(v.x) | ((unsigned int)f2bf(v.y) << 16);
        unsigned int hi = (unsigned int)f2bf(v.z) | ((unsigned int)f2bf(v.w) << 16);
        *(uint2*)&hs[row][c4] = make_uint2(lo, hi);
    }
    __syncthreads();

    int w = t >> 6, l = t & 63, lr = l & 15, lk = l >> 4;
    float a1v[2], a2v[2];
    #pragma unroll
    for (int j = 0; j < 2; ++j) {
        a1v[j] = a[(w * 2 + j) * 16 + lr];
        a2v[j] = a[FOUT + (w * 2 + j) * 16 + lr];
    }
    f32x4 acc[2] = {{0.f,0.f,0.f,0.f},{0.f,0.f,0.f,0.f}};

    #pragma unroll
    for (int kk = 0; kk < 8; ++kk) {
        int k0 = kk * 32;
        bf16x8 af = *(const bf16x8*)&hs[lr][k0 + lk * 8];
        #pragma unroll
        for (int j = 0; j < 2; ++j) {
            bf16x8 bfr = *(const bf16x8*)(WT + ((w * 2 + j) * 16 + lr) * 256 + k0 + lk * 8);
            acc[j] = __builtin_amdgcn_mfma_f32_16x16x32_bf16(af, bfr, acc[j], 0, 0, 0);
        }
    }

    int n0 = nglob0 & 2047;
    int sIdx = n0 >> 6;
    int hh   = (n0 >> 5) & 1;
    int bklo = (n0 & 31) >> 3;
    float v1[4] = {0.f,0.f,0.f,0.f}, v2[4] = {0.f,0.f,0.f,0.f};
    #pragma unroll
    for (int j = 0; j < 2; ++j) {
        int ot = w * 2 + j;
        float x0 = acc[j][0], x1 = acc[j][1], x2 = acc[j][2], x3 = acc[j][3];
        ushort4 pk;
        pk.x = f2bf(x0); pk.y = f2bf(x1); pk.z = f2bf(x2); pk.w = f2bf(x3);
        size_t fragBase = (((size_t)(b * 8 + ot) * 32 + sIdx) * 2 + hh) * 64;
        size_t lane = fragBase + lr + 16 * (bklo + (lk >> 1));
        *(ushort4*)(WhB + lane * 8 + (lk & 1) * 4) = pk;
        v1[0] += x0 * a1v[j]; v1[1] += x1 * a1v[j]; v1[2] += x2 * a1v[j]; v1[3] += x3 * a1v[j];
        v2[0] += x0 * a2v[j]; v2[1] += x1 * a2v[j]; v2[2] += x2 * a2v[j]; v2[3] += x3 * a2v[j];
    }
    #pragma unroll
    for (int m = 1; m < 16; m <<= 1)
        #pragma unroll
        for (int r = 0; r < 4; ++r) {
            v1[r] += __shfl_xor(v1[r], m);
            v2[r] += __shfl_xor(v2[r], m);
        }
    if (lr == 0)
        #pragma unroll
        for (int r = 0; r < 4; ++r) {
            s1w[w][lk * 4 + r] = v1[r];
            s2w[w][lk * 4 + r] = v2[r];
        }
    __syncthreads();
    if (t < 16) {
        s1[nglob0 + t] = s1w[0][t] + s1w[1][t] + s1w[2][t] + s1w[3][t];
        s2[nglob0 + t] = s2w[0][t] + s2w[1][t] + s2w[2][t] + s2w[3][t];
    }
}

// ---------------- Kernel 2: attention — adj streamed in-loop --------------
// R18 base. NEW: (1) Ps pad 76 (38 dwords == 6 mod 32 -> conflict-free MFMA
// A-reads; pad-72 cost 4.37M conflict-cycles = ~7 us/CU-aggregate);
// (2) adj prologue DELETED: lane (lr,lk) loads its own 4 int4 of adj per
// step via a 2-deep register ring (copy-locals-then-refill, lgkm-only
// barrier keeps them in flight) -> 64 MB adj stream fully overlapped,
// masks used directly from int regs (no nibble pack/unpack).
__global__ __launch_bounds__(256) void k_attn(const int* __restrict__ adj,
                                              const unsigned short* __restrict__ WhB,
                                              const float* __restrict__ s1,
                                              const float* __restrict__ s2,
                                              unsigned short* __restrict__ num,
                                              float* __restrict__ Zp) {
    __shared__ union {
        unsigned short Ps[2][64][76];              // P tile bf16, dbuf (19.5 KB)
        float hS[64][132];                         // epilogue transpose (33.8 KB)
    } S;
    __shared__ float s2S[JCH];                     // 2 KB

    int t = threadIdx.x, w = t >> 6, l = t & 63, lr = l & 15, lk = l >> 4;
    // XCD-aware bijective swizzle (grid 512 = 8 * 64)
    int bid = blockIdx.x;
    int bi = (bid >> 3) + (bid & 7) * 64;
    int part = bi >> 7, rem = bi & 127;
    int b = rem >> 5, i0 = (rem & 31) * 64, j0 = part * JCH;

    // ---- staging: s2 chunk only ----
    if (t < 128) ((float4*)s2S)[t] = ((const float4*)(s2 + b * NN + j0))[t];
    float s1r = s1[b * NN + i0 + w * 16 + lr];

    // ---- adj ring: lane (lr,lk) owns row i0+w*16+lr, j lk*16..+15 ----
    const int* aRow = adj + ((size_t)(b * NN) + i0 + w * 16 + lr) * NN + j0 + lk * 16;
    int4 av[2][4];
    #pragma unroll
    for (int s = 0; s < 2; ++s)
        #pragma unroll
        for (int q = 0; q < 4; ++q)
            av[s][q] = *(const int4*)(aRow + s * 64 + q * 4);

    // ---- B prefetch: wave w covers ot = 2w, 2w+1; 2-deep ring in regs ----
    const unsigned short* B0 = WhB + (((size_t)(b * 8 + w * 2) * 32 + part * NSTEP) * 2) * 512 + (size_t)l * 8;
    const unsigned short* B1 = B0 + (size_t)32 * 2 * 512;   // next ot
    bf16x8 bB[2][2][2];                            // [buf][ot2][hh]
    #pragma unroll
    for (int s = 0; s < 2; ++s) {
        bB[s][0][0] = *(const bf16x8*)(B0 + s * 1024);
        bB[s][0][1] = *(const bf16x8*)(B0 + s * 1024 + 512);
        bB[s][1][0] = *(const bf16x8*)(B1 + s * 1024);
        bB[s][1][1] = *(const bf16x8*)(B1 + s * 1024 + 512);
    }

    f32x4 acc[4][2];
    #pragma unroll
    for (int rg = 0; rg < 4; ++rg) {
        acc[rg][0] = (f32x4){0.f,0.f,0.f,0.f};
        acc[rg][1] = (f32x4){0.f,0.f,0.f,0.f};
    }
    float zacc = 0.f;

    __syncthreads();                               // s2S visible (one-time drain)

    #pragma unroll
    for (int s = 0; s < NSTEP; ++s) {
        const int slot = s & 1;
        // ---- copy adj to locals, refill ring slot ----
        int4 m0 = av[slot][0], m1 = av[slot][1], m2 = av[slot][2], m3 = av[slot][3];
        if (s < NSTEP - 2) {
            #pragma unroll
            for (int q = 0; q < 4; ++q)
                av[slot][q] = *(const int4*)(aRow + (s + 2) * 64 + q * 4);
        }

        // ---- P-phase: lane covers (row lr, j lk*16..+15) ----
        {
            int mv[16] = {m0.x, m0.y, m0.z, m0.w, m1.x, m1.y, m1.z, m1.w,
                          m2.x, m2.y, m2.z, m2.w, m3.x, m3.y, m3.z, m3.w};
            const float* sp = &s2S[s * 64 + lk * 16];
            float4 f0 = *(const float4*)sp,       f1 = *(const float4*)(sp + 4);
            float4 f2 = *(const float4*)(sp + 8), f3 = *(const float4*)(sp + 12);
            float sv[16] = {f0.x,f0.y,f0.z,f0.w, f1.x,f1.y,f1.z,f1.w,
                            f2.x,f2.y,f2.z,f2.w, f3.x,f3.y,f3.z,f3.w};
            unsigned int pw[8];
            #pragma unroll
            for (int q = 0; q < 8; ++q) {
                float e0 = s1r + sv[2 * q];
                float e1 = s1r + sv[2 * q + 1];
                e0 = fmaxf(e0, 0.2f * e0);
                e1 = fmaxf(e1, 0.2f * e1);
                float p0 = (mv[2 * q]     > 0) ? __expf(e0) : 0.f;
                float p1 = (mv[2 * q + 1] > 0) ? __expf(e1) : 0.f;
                zacc += p0 + p1;
                pw[q] = (unsigned int)f2bf(p0) | ((unsigned int)f2bf(p1) << 16);
            }
            *(uint4*)&S.Ps[slot][w * 16 + lr][lk * 16]     = (uint4){pw[0], pw[1], pw[2], pw[3]};
            *(uint4*)&S.Ps[slot][w * 16 + lr][lk * 16 + 8] = (uint4){pw[4], pw[5], pw[6], pw[7]};
        }
        asm volatile("s_waitcnt lgkmcnt(0)" ::: "memory");
        __builtin_amdgcn_s_barrier();
        __builtin_amdgcn_sched_barrier(0);

        // ---- copy B to locals, refill ring slot (independent, no drain) ----
        bf16x8 c00 = bB[slot][0][0], c01 = bB[slot][0][1];
        bf16x8 c10 = bB[slot][1][0], c11 = bB[slot][1][1];
        if (s < NSTEP - 2) {
            bB[slot][0][0] = *(const bf16x8*)(B0 + (s + 2) * 1024);
            bB[slot][0][1] = *(const bf16x8*)(B0 + (s + 2) * 1024 + 512);
            bB[slot][1][0] = *(const bf16x8*)(B1 + (s + 2) * 1024);
            bB[slot][1][1] = *(const bf16x8*)(B1 + (s + 2) * 1024 + 512);
        }

        // ---- MFMA: 4 row-groups x 2 ot x 2 hh = 16 MFMAs ----
        #pragma unroll
        for (int rg = 0; rg < 4; ++rg) {
            bf16x8 a0 = *(const bf16x8*)&S.Ps[slot][rg * 16 + lr][lk * 8];
            bf16x8 a1 = *(const bf16x8*)&S.Ps[slot][rg * 16 + lr][32 + lk * 8];
            acc[rg][0] = __builtin_amdgcn_mfma_f32_16x16x32_bf16(a0, c00, acc[rg][0], 0, 0, 0);
            acc[rg][0] = __builtin_amdgcn_mfma_f32_16x16x32_bf16(a1, c01, acc[rg][0], 0, 0, 0);
            acc[rg][1] = __builtin_amdgcn_mfma_f32_16x16x32_bf16(a0, c10, acc[rg][1], 0, 0, 0);
            acc[rg][1] = __builtin_amdgcn_mfma_f32_16x16x32_bf16(a1, c11, acc[rg][1], 0, 0, 0);
        }
    }

    // ---- Z partial for wave's rows (sum over lk) ----
    zacc += __shfl_xor(zacc, 16);
    zacc += __shfl_xor(zacc, 32);
    if (l < 16) Zp[(size_t)(part * NB + b) * NN + i0 + w * 16 + l] = zacc;

    // ---- epilogue: acc -> LDS (union reuse) -> coalesced bf16 stores ----
    __syncthreads();                               // Ps dead for all waves
    #pragma unroll
    for (int rg = 0; rg < 4; ++rg)
        #pragma unroll
        for (int ot2 = 0; ot2 < 2; ++ot2)
            #pragma unroll
            for (int r = 0; r < 4; ++r)
                S.hS[rg * 16 + lk * 4 + r][(w * 2 + ot2) * 16 + lr] = acc[rg][ot2][r];
    __syncthreads();

    unsigned short* np = num + ((size_t)(part * NB + b) * NN + i0) * FOUT;
    #pragma unroll
    for (int q = 0; q < 4; ++q) {
        int flat = q * 256 + t;                    // 0..1023
        int row = flat >> 4, c8 = (flat & 15) * 8;
        float4 v0 = *(const float4*)&S.hS[row][c8];
        float4 v1 = *(const float4*)&S.hS[row][c8 + 4];
        uint4 pk;
        pk.x = (unsigned int)f2bf(v0.x) | ((unsigned int)f2bf(v0.y) << 16);
        pk.y = (unsigned int)f2bf(v0.z) | ((unsigned int)f2bf(v0.w) << 16);
        pk.z = (unsigned int)f2bf(v1.x) | ((unsigned int)f2bf(v1.y) << 16);
        pk.w = (unsigned int)f2bf(v1.z) | ((unsigned int)f2bf(v1.w) << 16);
        *(uint4*)(np + (size_t)row * FOUT + c8) = pk;
    }
}

// ---------------- Kernel 3: reduce bf16 splits + LayerNorm + GELU ---------
__global__ __launch_bounds__(256) void k_final(const unsigned short* __restrict__ num,
                                               const float* __restrict__ Zp,
                                               const float* __restrict__ gamma,
                                               const float* __restrict__ beta,
                                               float* __restrict__ out) {
    int t = threadIdx.x, bi = blockIdx.x;
    int rowA = t >> 5;
    int c0 = (t & 31) * 4;
    size_t gn = (size_t)bi * 8 + rowA;
    int b = (int)(gn >> 11), n = (int)(gn & 2047);

    float Z = 0.f;
    #pragma unroll
    for (int p = 0; p < SPLIT; ++p) Z += Zp[(size_t)(p * NB + b) * NN + n];

    float x[4] = {0.f, 0.f, 0.f, 0.f};
    #pragma unroll
    for (int p = 0; p < SPLIT; ++p) {
        const unsigned short* np = num + ((size_t)(p * NB + b) * NN + n) * FOUT + c0;
        ushort4 u = *(const ushort4*)np;
        x[0] += bf2f(u.x); x[1] += bf2f(u.y); x[2] += bf2f(u.z); x[3] += bf2f(u.w);
    }
    float rz = 1.f / Z;
    #pragma unroll
    for (int i = 0; i < 4; ++i) x[i] *= rz;

    float sm = 0.f, sq = 0.f;
    #pragma unroll
    for (int i = 0; i < 4; ++i) { sm += x[i]; sq += x[i] * x[i]; }
    #pragma unroll
    for (int m = 1; m < 32; m <<= 1) {
        sm += __shfl_xor(sm, m);
        sq += __shfl_xor(sq, m);
    }
    float mu  = sm * (1.f / 128.f);
    float var = sq * (1.f / 128.f) - mu * mu;
    float rs  = rsqrtf(var + 1e-5f);
    float4 g0 = *(const float4*)(gamma + c0);
    float4 e0 = *(const float4*)(beta + c0);
    float gg[4] = {g0.x, g0.y, g0.z, g0.w};
    float bb[4] = {e0.x, e0.y, e0.z, e0.w};
    float y[4];
    #pragma unroll
    for (int i = 0; i < 4; ++i) {
        float v = (x[i] - mu) * rs * gg[i] + bb[i];
        y[i] = 0.5f * v * (1.f + erff(v * 0.70710678118f));
    }
    float* op = out + gn * FOUT + c0;
    *(float4*)op = make_float4(y[0], y[1], y[2], y[3]);
}

// ---------------- launcher ----------------
extern "C" void kernel_launch(void* const* d_in, const int* in_sizes, int n_in,
                              void* d_out, int out_size, void* d_ws, size_t ws_size,
                              hipStream_t stream) {
    const float* h     = (const float*)d_in[0];
    const int*   adj   = (const int*)d_in[1];
    const float* W     = (const float*)d_in[2];
    const float* a     = (const float*)d_in[3];
    const float* gamma = (const float*)d_in[4];
    const float* beta  = (const float*)d_in[5];
    float* out = (float*)d_out;

    char* ws = (char*)d_ws;
    unsigned short* WT  = (unsigned short*)ws;                       // 64 KiB
    unsigned short* WhB = (unsigned short*)(ws + (1u << 16));        // 2 MiB
    float* s1 = (float*)(ws + 2162688);                              // 32 KiB
    float* s2 = (float*)(ws + 2195456);                              // 32 KiB
    float* Zp = (float*)(ws + 2228224);                              // 128 KiB
    unsigned short* num = (unsigned short*)(ws + 2359296);           // 8 MiB

    hipLaunchKernelGGL(k_wt,    dim3(128),  dim3(256), 0, stream, W, WT);
    hipLaunchKernelGGL(k_wh,    dim3(512),  dim3(256), 0, stream, h, a, WT, WhB, s1, s2);
    hipLaunchKernelGGL(k_attn,  dim3(512),  dim3(256), 0, stream, adj, WhB, s1, s2, num, Zp);
    hipLaunchKernelGGL(k_final, dim3(1024), dim3(256), 0, stream, num, Zp, gamma, beta, out);
}